// Round 3
// baseline (102.090 us; speedup 1.0000x reference)
//
#include <hip/hip_runtime.h>
#include <math.h>

// Problem constants (from reference)
//   stimulus: (32, 128*256) f32   -> q (32, 128, 256)
//   H_real/H_imag: (512, 256, 3) f32
//   out: (32, 512) f32
// Pipeline:
//   1) fft2 over (128, 256): separable -> row FFT(256) then col FFT(128)
//   2) per (b, m): row r = m % 128; for w in 0..2:
//        y = unnormalized_ifft256(qf[b,r,:] * H[m,:,w]); acc += sum|y|
//      (ref_beams have |.|=1 and ifft is linear -> they vanish under abs)
//   3) focused = acc / (256*256*3); out = focused > 0.3 ? focused : 0

#define TWO_PI 6.28318530717958647692f

__device__ inline float2 cmul(float2 a, float2 b) {
    return make_float2(a.x * b.x - a.y * b.y, a.x * b.y + a.y * b.x);
}

// ---------------- Pass 1: length-256 forward FFT along D, real input ----------
// grid = B*R = 4096 blocks, 128 threads. In LDS, radix-2 DIT (bit-reversed load).
__global__ __launch_bounds__(128) void k_fft_rows(const float* __restrict__ x,
                                                  float2* __restrict__ y) {
    __shared__ float2 s[256];
    __shared__ float2 tw[128];  // W_256^k, forward sign
    const int t = threadIdx.x;  // 0..127

    {
        float ang = -TWO_PI * (float)t * (1.0f / 256.0f);
        float sn, cs;
        __sincosf(ang, &sn, &cs);
        tw[t] = make_float2(cs, sn);
    }

    const float* xr = x + (size_t)blockIdx.x * 256;
#pragma unroll
    for (int i = t; i < 256; i += 128) {
        s[__brev((unsigned)i) >> 24] = make_float2(xr[i], 0.0f);
    }
    __syncthreads();

#pragma unroll
    for (int st = 0; st < 8; ++st) {        // half = 1<<st
        const int half = 1 << st;
        const int pos  = t & (half - 1);
        const int i0   = (t << 1) - pos;
        const int i1   = i0 + half;
        const float2 w = tw[pos << (7 - st)];
        const float2 a = s[i0];
        const float2 bv = cmul(s[i1], w);
        __syncthreads();  // reads done before writes (radix-2 in-place is disjoint,
                          // but i0/i1 of one thread are another's only across stages)
        s[i0] = make_float2(a.x + bv.x, a.y + bv.y);
        s[i1] = make_float2(a.x - bv.x, a.y - bv.y);
        __syncthreads();
    }

    float2* yr = y + (size_t)blockIdx.x * 256;
#pragma unroll
    for (int i = t; i < 256; i += 128) yr[i] = s[i];
}

// ---------------- Pass 2: length-128 forward FFT along R, in place ------------
// grid = B * 8 tiles (32 columns each) = 256 blocks, 256 threads.
__global__ __launch_bounds__(256) void k_fft_cols(float2* __restrict__ y) {
    __shared__ float2 sm[128][33];  // +1 pad breaks power-of-2 bank stride
    __shared__ float2 tw[64];       // W_128^k, forward sign
    const int tid = threadIdx.x;

    if (tid < 64) {
        float ang = -TWO_PI * (float)tid * (1.0f / 128.0f);
        float sn, cs;
        __sincosf(ang, &sn, &cs);
        tw[tid] = make_float2(cs, sn);
    }

    const int b  = blockIdx.x >> 3;
    const int d0 = (blockIdx.x & 7) << 5;
    const int c  = tid & 31;
    const int r0 = tid >> 5;  // 0..7
    const size_t base = ((size_t)b * 128) * 256 + (size_t)d0 + (size_t)c;

#pragma unroll
    for (int r = r0; r < 128; r += 8) {
        sm[__brev((unsigned)r) >> 25][c] = y[base + (size_t)r * 256];
    }
    __syncthreads();

#pragma unroll
    for (int st = 0; st < 7; ++st) {  // half = 1<<st
        const int half = 1 << st;
#pragma unroll
        for (int k = 0; k < 8; ++k) {  // 64 butterflies x 32 cols / 256 threads
            const int idx = tid + (k << 8);
            const int cc  = idx & 31;
            const int j   = idx >> 5;  // 0..63
            const int pos = j & (half - 1);
            const int i0  = (j << 1) - pos;
            const int i1  = i0 + half;
            const float2 w  = tw[pos << (6 - st)];
            const float2 a  = sm[i0][cc];
            const float2 bv = cmul(sm[i1][cc], w);
            sm[i0][cc] = make_float2(a.x + bv.x, a.y + bv.y);
            sm[i1][cc] = make_float2(a.x - bv.x, a.y - bv.y);
        }
        __syncthreads();
    }

#pragma unroll
    for (int r = r0; r < 128; r += 8) {
        y[base + (size_t)r * 256] = sm[r][c];
    }
}

// ---------------- Pass 3: per (b,m): 3x inverse FFT(256) + |.| reduction ------
// grid = B*512 = 16384 blocks, 64 threads (1 wave).
__global__ __launch_bounds__(64) void k_recon(const float2* __restrict__ qf,
                                              const float* __restrict__ Hr,
                                              const float* __restrict__ Hi,
                                              float* __restrict__ out) {
    __shared__ float2 s[256];
    __shared__ float2 qrow[256];
    __shared__ float hre[768];
    __shared__ float him[768];
    __shared__ float2 tw[128];  // W_256^{-k} -> inverse sign (+)

    const int t  = threadIdx.x;  // 0..63
    const int bm = blockIdx.x;
    const int b  = bm >> 9;
    const int m  = bm & 511;
    const int r  = m & 127;

#pragma unroll
    for (int i = t; i < 128; i += 64) {
        float ang = TWO_PI * (float)i * (1.0f / 256.0f);  // + for inverse
        float sn, cs;
        __sincosf(ang, &sn, &cs);
        tw[i] = make_float2(cs, sn);
    }

    const float2* q = qf + ((size_t)(b * 128 + r)) * 256;
#pragma unroll
    for (int i = t; i < 256; i += 64) qrow[i] = q[i];

    const float* hr_g = Hr + (size_t)m * 768;
    const float* hi_g = Hi + (size_t)m * 768;
#pragma unroll
    for (int i = t; i < 768; i += 64) {
        hre[i] = hr_g[i];
        him[i] = hi_g[i];
    }

    float acc = 0.0f;
    for (int w = 0; w < 3; ++w) {
        __syncthreads();  // w=0: loads visible; w>0: prior |.| reads done
#pragma unroll
        for (int i = t; i < 256; i += 64) {
            const float2 h = make_float2(hre[i * 3 + w], him[i * 3 + w]);
            s[__brev((unsigned)i) >> 24] = cmul(qrow[i], h);
        }
        __syncthreads();

#pragma unroll
        for (int st = 0; st < 8; ++st) {  // half = 1<<st
            const int half = 1 << st;
#pragma unroll
            for (int k = 0; k < 2; ++k) {  // 128 butterflies / 64 threads
                const int j   = t + (k << 6);
                const int pos = j & (half - 1);
                const int i0  = (j << 1) - pos;
                const int i1  = i0 + half;
                const float2 wv = tw[pos << (7 - st)];
                const float2 a  = s[i0];
                const float2 bv = cmul(s[i1], wv);
                s[i0] = make_float2(a.x + bv.x, a.y + bv.y);
                s[i1] = make_float2(a.x - bv.x, a.y - bv.y);
            }
            __syncthreads();
        }

#pragma unroll
        for (int i = t; i < 256; i += 64) {
            const float2 v = s[i];
            acc += sqrtf(v.x * v.x + v.y * v.y);
        }
    }

    // wave-level reduction over 64 lanes
#pragma unroll
    for (int off = 32; off > 0; off >>= 1) acc += __shfl_xor(acc, off, 64);

    if (t == 0) {
        const float focused = acc * (1.0f / (256.0f * 256.0f * 3.0f));
        out[bm] = (focused > 0.3f) ? focused : 0.0f;
    }
}

extern "C" void kernel_launch(void* const* d_in, const int* in_sizes, int n_in,
                              void* d_out, int out_size, void* d_ws, size_t ws_size,
                              hipStream_t stream) {
    (void)in_sizes; (void)n_in; (void)out_size; (void)ws_size;
    const float* stim = (const float*)d_in[0];   // (32, 32768)
    const float* Hr   = (const float*)d_in[1];   // (512, 256, 3)
    const float* Hi   = (const float*)d_in[2];   // (512, 256, 3)
    float* out = (float*)d_out;                  // (32, 512)
    float2* y  = (float2*)d_ws;                  // 32*128*256 complex = 8 MB

    k_fft_rows<<<32 * 128, 128, 0, stream>>>(stim, y);
    k_fft_cols<<<32 * 8, 256, 0, stream>>>(y);
    k_recon<<<32 * 512, 64, 0, stream>>>(y, Hr, Hi, out);
}

// Round 4
// 67.055 us; speedup vs baseline: 1.5225x; 1.5225x over previous
//
#include <hip/hip_runtime.h>
#include <math.h>

// Problem: stimulus (32, 128*256) f32; H_real/H_imag (512, 256, 3) f32; out (32, 512) f32.
// Pipeline:
//   qf = fft2(q) over (128, 256)  [separable]
//   per (b,m): r = m%128; acc = sum_w sum_d |ifft256(qf[b,r,:] * H[m,:,w])|
//   out = acc/(256*256*3), thresholded at 0.3    (unit-modulus ref_beams vanish under |.|)
//
// Ordering trick: forward k-axis FFT is DIF (natural in -> bitrev content out at natural
// slots); the recon inverse FFT is DIT (bitrev in -> natural out). The pointwise multiply
// happens in bitrev index space, with H pre-permuted once (k_ht). Output order of the
// inverse FFT is irrelevant (we only sum |.|), so NO bit-reversal permutes anywhere.
// All 256-pt FFTs are register-resident: lane l owns elements {l, l+64, l+128, l+192};
// strides 64/128 are in-register, strides 1..32 are __shfl_xor stages. No LDS, no barriers.

#define TWO_PI 6.28318530717958647692f
#define PI_F   3.14159265358979323846f

__device__ inline float2 cmul(float2 a, float2 b) {
    return make_float2(a.x * b.x - a.y * b.y, a.x * b.y + a.y * b.x);
}
__device__ inline float2 cadd(float2 a, float2 b) { return make_float2(a.x + b.x, a.y + b.y); }
__device__ inline float2 csub(float2 a, float2 b) { return make_float2(a.x - b.x, a.y - b.y); }
__device__ inline float2 shfl_xor_c(float2 v, int mask) {
    return make_float2(__shfl_xor(v.x, mask, 64), __shfl_xor(v.y, mask, 64));
}

// ---------------- H transpose + bitrev pre-pass --------------------------------
// Ht[m][w][p] = (Hr + i*Hi)[m][brev8(p)][w].  512*3*256 float2 = 3 MB.
__global__ __launch_bounds__(256) void k_ht(const float* __restrict__ Hr,
                                            const float* __restrict__ Hi,
                                            float2* __restrict__ Ht) {
    const int idx = blockIdx.x * 256 + threadIdx.x;   // < 512*768
    const int m = idx / 768;
    const int rem = idx - m * 768;
    const int w = rem >> 8;          // 0..2
    const int p = rem & 255;
    const int k = __brev((unsigned)p) >> 24;
    const int src = (m * 256 + k) * 3 + w;
    Ht[idx] = make_float2(Hr[src], Hi[src]);
}

// ---------------- Pass 1: 256-pt forward DIF FFT per row, register-resident ----
// 4096 rows, 1 wave each, 4 waves/block. Natural real input -> bitrev content out.
__global__ __launch_bounds__(256) void k_fft_rows(const float* __restrict__ x,
                                                  float2* __restrict__ y) {
    const int lane = threadIdx.x & 63;
    const int wid  = blockIdx.x * 4 + (threadIdx.x >> 6);   // row id 0..4095
    const float fl = (float)lane;

    // forward twiddles (sign -)
    float sn, cs;
    __sincosf(-TWO_PI * fl * (1.0f / 256.0f), &sn, &cs);
    const float2 w128_0 = make_float2(cs, sn);                 // exp(-2pi i l/256)
    const float2 w128_1 = make_float2(w128_0.y, -w128_0.x);    // * exp(-i pi/2)
    __sincosf(-TWO_PI * fl * (1.0f / 128.0f), &sn, &cs);
    const float2 w64 = make_float2(cs, sn);                    // exp(-2pi i l/128)
    float2 wst[6];   // cross-lane DIF stages h=32,16,8,4,2,1: exp(-pi i (l&(h-1))/h)
#pragma unroll
    for (int s = 0; s < 6; ++s) {
        const int h = 32 >> s;
        __sincosf(-PI_F * (float)(lane & (h - 1)) / (float)h, &sn, &cs);
        wst[s] = make_float2(cs, sn);
    }

    const float* xr = x + (size_t)wid * 256;
    float2 v0 = make_float2(xr[lane],       0.0f);
    float2 v1 = make_float2(xr[64 + lane],  0.0f);
    float2 v2 = make_float2(xr[128 + lane], 0.0f);
    float2 v3 = make_float2(xr[192 + lane], 0.0f);

    // DIF h=128: pairs (v0,v2),(v1,v3)
    { float2 a = v0, b = v2; v0 = cadd(a, b); v2 = cmul(csub(a, b), w128_0); }
    { float2 a = v1, b = v3; v1 = cadd(a, b); v3 = cmul(csub(a, b), w128_1); }
    // DIF h=64: pairs (v0,v1),(v2,v3)
    { float2 a = v0, b = v1; v0 = cadd(a, b); v1 = cmul(csub(a, b), w64); }
    { float2 a = v2, b = v3; v2 = cadd(a, b); v3 = cmul(csub(a, b), w64); }
    // cross-lane DIF h=32..1
    float2 v[4] = {v0, v1, v2, v3};
#pragma unroll
    for (int s = 0; s < 6; ++s) {
        const int h = 32 >> s;
        const bool up = (lane & h) != 0;
        const float2 w = wst[s];
#pragma unroll
        for (int j = 0; j < 4; ++j) {
            const float2 o = shfl_xor_c(v[j], h);
            const float2 r = up ? csub(o, v[j]) : cadd(v[j], o);
            v[j] = up ? cmul(r, w) : r;
        }
    }

    float2* yr = y + (size_t)wid * 256;
#pragma unroll
    for (int j = 0; j < 4; ++j) yr[j * 64 + lane] = v[j];
}

// ---------------- Pass 2: 128-pt forward DIT FFT along r, in place (LDS, padded)
// grid = B * 8 tiles (32 k-slots each) = 256 blocks, 256 threads.
// Natural content out along r (bitrev on load).
__global__ __launch_bounds__(256) void k_fft_cols(float2* __restrict__ y) {
    __shared__ float2 sm[128][33];
    __shared__ float2 tw[64];
    const int tid = threadIdx.x;

    if (tid < 64) {
        float sn, cs;
        __sincosf(-TWO_PI * (float)tid * (1.0f / 128.0f), &sn, &cs);
        tw[tid] = make_float2(cs, sn);
    }

    const int b  = blockIdx.x >> 3;
    const int d0 = (blockIdx.x & 7) << 5;
    const int c  = tid & 31;
    const int r0 = tid >> 5;
    const size_t base = ((size_t)b * 128) * 256 + (size_t)d0 + (size_t)c;

#pragma unroll
    for (int r = r0; r < 128; r += 8) {
        sm[__brev((unsigned)r) >> 25][c] = y[base + (size_t)r * 256];
    }
    __syncthreads();

#pragma unroll
    for (int st = 0; st < 7; ++st) {
        const int half = 1 << st;
#pragma unroll
        for (int k = 0; k < 8; ++k) {
            const int idx = tid + (k << 8);
            const int cc  = idx & 31;
            const int j   = idx >> 5;
            const int pos = j & (half - 1);
            const int i0  = (j << 1) - pos;
            const int i1  = i0 + half;
            const float2 w  = tw[pos << (6 - st)];
            const float2 a  = sm[i0][cc];
            const float2 bv = cmul(sm[i1][cc], w);
            sm[i0][cc] = cadd(a, bv);
            sm[i1][cc] = csub(a, bv);
        }
        __syncthreads();
    }

#pragma unroll
    for (int r = r0; r < 128; r += 8) {
        y[base + (size_t)r * 256] = sm[r][c];
    }
}

// ---------------- Pass 3: per (b,m): 3x inverse 256-pt DIT FFT, register-resident
// 16384 tasks, 1 wave each, 4 waves/block. Bitrev content in -> natural out; sum |.|.
__global__ __launch_bounds__(256) void k_recon(const float2* __restrict__ qf,
                                               const float2* __restrict__ Ht,
                                               float* __restrict__ out) {
    const int lane = threadIdx.x & 63;
    const int task = blockIdx.x * 4 + (threadIdx.x >> 6);  // b*512 + m
    const int b = task >> 9;
    const int m = task & 511;
    const int r = m & 127;
    const float fl = (float)lane;

    // inverse twiddles (sign +)
    float sn, cs;
    float2 wst[6];   // cross-lane DIT stages h=1,2,4,8,16,32: exp(+pi i (l&(h-1))/h)
#pragma unroll
    for (int s = 0; s < 6; ++s) {
        const int h = 1 << s;
        __sincosf(PI_F * (float)(lane & (h - 1)) / (float)h, &sn, &cs);
        wst[s] = make_float2(cs, sn);
    }
    __sincosf(TWO_PI * fl * (1.0f / 128.0f), &sn, &cs);
    const float2 w64 = make_float2(cs, sn);                   // exp(+2pi i l/128)
    __sincosf(TWO_PI * fl * (1.0f / 256.0f), &sn, &cs);
    const float2 wi128_0 = make_float2(cs, sn);               // exp(+2pi i l/256)
    const float2 wi128_1 = make_float2(-wi128_0.y, wi128_0.x);// * exp(+i pi/2)

    const float2* q = qf + ((size_t)(b * 128 + r)) * 256;
    float2 qv[4];
#pragma unroll
    for (int j = 0; j < 4; ++j) qv[j] = q[j * 64 + lane];

    float acc = 0.0f;
#pragma unroll
    for (int w = 0; w < 3; ++w) {
        const float2* h = Ht + ((size_t)(m * 3 + w)) * 256;
        float2 v[4];
#pragma unroll
        for (int j = 0; j < 4; ++j) v[j] = cmul(qv[j], h[j * 64 + lane]);

        // cross-lane DIT h=1..32
#pragma unroll
        for (int s = 0; s < 6; ++s) {
            const int hh = 1 << s;
            const bool up = (lane & hh) != 0;
            const float2 wv = wst[s];
#pragma unroll
            for (int j = 0; j < 4; ++j) {
                const float2 o  = shfl_xor_c(v[j], hh);
                const float2 bb = up ? v[j] : o;   // element at p+h
                const float2 aa = up ? o : v[j];   // element at p
                const float2 t  = cmul(wv, bb);
                v[j] = up ? csub(aa, t) : cadd(aa, t);
            }
        }
        // in-register DIT h=64: pairs (0,1),(2,3)
        {
            float2 t = cmul(w64, v[1]);
            float2 a = v[0];
            v[0] = cadd(a, t); v[1] = csub(a, t);
            t = cmul(w64, v[3]);
            a = v[2];
            v[2] = cadd(a, t); v[3] = csub(a, t);
        }
        // in-register DIT h=128: pairs (0,2) w/ wi128_0, (1,3) w/ wi128_1
        {
            float2 t = cmul(wi128_0, v[2]);
            float2 a = v[0];
            v[0] = cadd(a, t); v[2] = csub(a, t);
            t = cmul(wi128_1, v[3]);
            a = v[1];
            v[1] = cadd(a, t); v[3] = csub(a, t);
        }

#pragma unroll
        for (int j = 0; j < 4; ++j) {
            acc += sqrtf(v[j].x * v[j].x + v[j].y * v[j].y);
        }
    }

#pragma unroll
    for (int off = 32; off > 0; off >>= 1) acc += __shfl_xor(acc, off, 64);

    if (lane == 0) {
        const float focused = acc * (1.0f / (256.0f * 256.0f * 3.0f));
        out[task] = (focused > 0.3f) ? focused : 0.0f;
    }
}

extern "C" void kernel_launch(void* const* d_in, const int* in_sizes, int n_in,
                              void* d_out, int out_size, void* d_ws, size_t ws_size,
                              hipStream_t stream) {
    (void)in_sizes; (void)n_in; (void)out_size; (void)ws_size;
    const float* stim = (const float*)d_in[0];   // (32, 32768)
    const float* Hr   = (const float*)d_in[1];   // (512, 256, 3)
    const float* Hi   = (const float*)d_in[2];   // (512, 256, 3)
    float* out = (float*)d_out;                  // (32, 512)

    float2* y  = (float2*)d_ws;                              // 8 MB: qf slots
    float2* Ht = (float2*)((char*)d_ws + (size_t)32 * 128 * 256 * sizeof(float2)); // 3 MB

    k_ht<<<(512 * 768) / 256, 256, 0, stream>>>(Hr, Hi, Ht);
    k_fft_rows<<<4096 / 4, 256, 0, stream>>>(stim, y);
    k_fft_cols<<<32 * 8, 256, 0, stream>>>(y);
    k_recon<<<16384 / 4, 256, 0, stream>>>(y, Ht, out);
}

// Round 6
// 54.196 us; speedup vs baseline: 1.8837x; 1.2373x over previous
//
#include <hip/hip_runtime.h>
#include <math.h>

// Problem: stimulus (32, 128*256) f32; H_real/H_imag (512, 256, 3) f32; out (32, 512) f32.
//   qf = fft2(q) over (128, 256)  [separable]
//   per (b,m): r = m%128; acc = sum_w sum_d |ifft256(qf[b,r,:] * H[m,:,w])|
//   out = acc/(256*256*3), thresholded at 0.3   (unit-modulus ref_beams vanish under |.|)
//
// Ordering: forward k-axis FFT is DIF (natural in -> bitrev out), recon inverse is DIT
// (bitrev in -> natural out); pointwise multiply lives in bitrev space with H
// pre-permuted once. No bit-reversal permutes anywhere.
// All 256-pt FFTs register-resident: lane l owns {l, l+64, l+128, l+192}; cross-lane
// stages via __shfl_xor (known-good; round-5's raw ds_bpermute showed post-timing
// nondeterminism); butterflies select-free: v' = A*v + B*o with per-lane constants.
// h=1 stages have W==1 for all lanes -> collapsed to v' = (+/-1)*v + o.

#define TWO_PI 6.28318530717958647692f
#define PI_F   3.14159265358979323846f

__device__ inline float2 cmul(float2 a, float2 b) {
    return make_float2(a.x * b.x - a.y * b.y, a.x * b.y + a.y * b.x);
}
__device__ inline float2 cadd(float2 a, float2 b) { return make_float2(a.x + b.x, a.y + b.y); }
__device__ inline float2 csub(float2 a, float2 b) { return make_float2(a.x - b.x, a.y - b.y); }

// v' = A*v + B*o (complex). The A*v half is independent of the shuffle result.
__device__ inline float2 ab2(float2 A, float2 v, float2 B, float2 o) {
    return make_float2(A.x * v.x - A.y * v.y + B.x * o.x - B.y * o.y,
                       A.x * v.y + A.y * v.x + B.x * o.y + B.y * o.x);
}
__device__ inline float2 shfl_xor_c(float2 v, int mask) {
    return make_float2(__shfl_xor(v.x, mask, 64), __shfl_xor(v.y, mask, 64));
}

// ---------------- Pass 1 (fused): row FFTs + H transpose/bitrev ------------------
// blocks [0,1024): 256-pt forward DIF FFT per row (4096 rows, 1 wave each).
// blocks [1024,2560): Ht[m][w][p] = (Hr+i*Hi)[m][brev8(p)][w]  (512*3*256 float2).
__global__ __launch_bounds__(256) void k_prep(const float* __restrict__ x,
                                              float2* __restrict__ y,
                                              const float* __restrict__ Hr,
                                              const float* __restrict__ Hi,
                                              float2* __restrict__ Ht) {
    if (blockIdx.x >= 1024) {
        const int idx = (blockIdx.x - 1024) * 256 + threadIdx.x;  // < 512*768
        const int m = idx / 768;
        const int rem = idx - m * 768;
        const int w = rem >> 8;
        const int p = rem & 255;
        const int k = __brev((unsigned)p) >> 24;
        const int src = (m * 256 + k) * 3 + w;
        Ht[idx] = make_float2(Hr[src], Hi[src]);
        return;
    }

    const int lane = threadIdx.x & 63;
    const int wid  = blockIdx.x * 4 + (threadIdx.x >> 6);   // row id 0..4095
    const float fl = (float)lane;
    float sn, cs;

    // in-register stage twiddles (forward, sign -)
    __sincosf(-TWO_PI * fl * (1.0f / 256.0f), &sn, &cs);
    const float2 w128_0 = make_float2(cs, sn);
    const float2 w128_1 = make_float2(w128_0.y, -w128_0.x);
    __sincosf(-TWO_PI * fl * (1.0f / 128.0f), &sn, &cs);
    const float2 w64 = make_float2(cs, sn);

    // cross-lane DIF stages h=32..2: W = exp(-i pi (lane&(h-1))/h)
    // down: v' = v + o (A=1,B=1);  up: v' = (o - v)*W (A=-W, B=W)
    float2 A[5], Bc[5];
#pragma unroll
    for (int s = 0; s < 5; ++s) {
        const int h = 32 >> s;
        __sincosf(-PI_F * (float)(lane & (h - 1)) / (float)h, &sn, &cs);
        const float2 W = make_float2(cs, sn);
        const bool up = (lane & h) != 0;
        A[s]  = up ? make_float2(-W.x, -W.y) : make_float2(1.0f, 0.0f);
        Bc[s] = up ? W : make_float2(1.0f, 0.0f);
    }
    const float sgn1 = (lane & 1) ? -1.0f : 1.0f;  // h=1 stage: W==1

    const float* xr = x + (size_t)wid * 256;
    float2 v[4];
    v[0] = make_float2(xr[lane],       0.0f);
    v[1] = make_float2(xr[64 + lane],  0.0f);
    v[2] = make_float2(xr[128 + lane], 0.0f);
    v[3] = make_float2(xr[192 + lane], 0.0f);

    // DIF h=128: (v0,v2),(v1,v3)
    { float2 a = v[0], b = v[2]; v[0] = cadd(a, b); v[2] = cmul(csub(a, b), w128_0); }
    { float2 a = v[1], b = v[3]; v[1] = cadd(a, b); v[3] = cmul(csub(a, b), w128_1); }
    // DIF h=64: (v0,v1),(v2,v3)
    { float2 a = v[0], b = v[1]; v[0] = cadd(a, b); v[1] = cmul(csub(a, b), w64); }
    { float2 a = v[2], b = v[3]; v[2] = cadd(a, b); v[3] = cmul(csub(a, b), w64); }

    // cross-lane DIF h=32..2
#pragma unroll
    for (int s = 0; s < 5; ++s) {
        const int h = 32 >> s;
#pragma unroll
        for (int j = 0; j < 4; ++j) {
            const float2 o = shfl_xor_c(v[j], h);
            v[j] = ab2(A[s], v[j], Bc[s], o);
        }
    }
    // cross-lane DIF h=1: down v+o, up o-v
#pragma unroll
    for (int j = 0; j < 4; ++j) {
        const float2 o = shfl_xor_c(v[j], 1);
        v[j] = make_float2(fmaf(sgn1, v[j].x, o.x), fmaf(sgn1, v[j].y, o.y));
    }

    float2* yr = y + (size_t)wid * 256;
#pragma unroll
    for (int j = 0; j < 4; ++j) yr[j * 64 + lane] = v[j];
}

// ---------------- Pass 2: 128-pt forward DIT FFT along r, in place (LDS, padded) --
__global__ __launch_bounds__(256) void k_fft_cols(float2* __restrict__ y) {
    __shared__ float2 sm[128][33];
    __shared__ float2 tw[64];
    const int tid = threadIdx.x;

    if (tid < 64) {
        float sn, cs;
        __sincosf(-TWO_PI * (float)tid * (1.0f / 128.0f), &sn, &cs);
        tw[tid] = make_float2(cs, sn);
    }

    const int b  = blockIdx.x >> 3;
    const int d0 = (blockIdx.x & 7) << 5;
    const int c  = tid & 31;
    const int r0 = tid >> 5;
    const size_t base = ((size_t)b * 128) * 256 + (size_t)d0 + (size_t)c;

#pragma unroll
    for (int r = r0; r < 128; r += 8) {
        sm[__brev((unsigned)r) >> 25][c] = y[base + (size_t)r * 256];
    }
    __syncthreads();

#pragma unroll
    for (int st = 0; st < 7; ++st) {
        const int half = 1 << st;
#pragma unroll
        for (int k = 0; k < 8; ++k) {
            const int idx = tid + (k << 8);
            const int cc  = idx & 31;
            const int j   = idx >> 5;
            const int pos = j & (half - 1);
            const int i0  = (j << 1) - pos;
            const int i1  = i0 + half;
            const float2 w  = tw[pos << (6 - st)];
            const float2 a  = sm[i0][cc];
            const float2 bv = cmul(sm[i1][cc], w);
            sm[i0][cc] = cadd(a, bv);
            sm[i1][cc] = csub(a, bv);
        }
        __syncthreads();
    }

#pragma unroll
    for (int r = r0; r < 128; r += 8) {
        y[base + (size_t)r * 256] = sm[r][c];
    }
}

// ---------------- Pass 3: per (b,m): 3x inverse 256-pt DIT FFT, register-resident -
__global__ __launch_bounds__(256) void k_recon(const float2* __restrict__ qf,
                                               const float2* __restrict__ Ht,
                                               float* __restrict__ out) {
    const int lane = threadIdx.x & 63;
    const int task = blockIdx.x * 4 + (threadIdx.x >> 6);  // b*512 + m
    const int b = task >> 9;
    const int m = task & 511;
    const int r = m & 127;
    const float fl = (float)lane;
    float sn, cs;

    // cross-lane DIT stages h=2..32 (inverse, sign +): W = exp(+i pi (lane&(h-1))/h)
    // down: v' = v + W*o (A=1,B=W);  up: v' = o - W*v (A=-W, B=1)
    float2 A[5], Bc[5];
#pragma unroll
    for (int s = 0; s < 5; ++s) {
        const int h = 2 << s;
        __sincosf(PI_F * (float)(lane & (h - 1)) / (float)h, &sn, &cs);
        const float2 W = make_float2(cs, sn);
        const bool up = (lane & h) != 0;
        A[s]  = up ? make_float2(-W.x, -W.y) : make_float2(1.0f, 0.0f);
        Bc[s] = up ? make_float2(1.0f, 0.0f) : W;
    }
    const float sgn1 = (lane & 1) ? -1.0f : 1.0f;  // h=1 stage: W==1
    __sincosf(TWO_PI * fl * (1.0f / 128.0f), &sn, &cs);
    const float2 w64 = make_float2(cs, sn);
    __sincosf(TWO_PI * fl * (1.0f / 256.0f), &sn, &cs);
    const float2 wi128_0 = make_float2(cs, sn);
    const float2 wi128_1 = make_float2(-wi128_0.y, wi128_0.x);

    const float2* q = qf + ((size_t)(b * 128 + r)) * 256;
    float2 qv[4];
#pragma unroll
    for (int j = 0; j < 4; ++j) qv[j] = q[j * 64 + lane];

    float acc = 0.0f;
#pragma unroll
    for (int w = 0; w < 3; ++w) {
        const float2* hp = Ht + ((size_t)(m * 3 + w)) * 256;
        float2 v[4];
#pragma unroll
        for (int j = 0; j < 4; ++j) v[j] = cmul(qv[j], hp[j * 64 + lane]);

        // cross-lane DIT h=1: down v+o, up o-v
#pragma unroll
        for (int j = 0; j < 4; ++j) {
            const float2 o = shfl_xor_c(v[j], 1);
            v[j] = make_float2(fmaf(sgn1, v[j].x, o.x), fmaf(sgn1, v[j].y, o.y));
        }
        // cross-lane DIT h=2..32
#pragma unroll
        for (int s = 0; s < 5; ++s) {
            const int h = 2 << s;
#pragma unroll
            for (int j = 0; j < 4; ++j) {
                const float2 o = shfl_xor_c(v[j], h);
                v[j] = ab2(A[s], v[j], Bc[s], o);
            }
        }
        // in-register DIT h=64: (0,1),(2,3)
        {
            float2 t = cmul(w64, v[1]);
            float2 a = v[0];
            v[0] = cadd(a, t); v[1] = csub(a, t);
            t = cmul(w64, v[3]);
            a = v[2];
            v[2] = cadd(a, t); v[3] = csub(a, t);
        }
        // in-register DIT h=128: (0,2) w/ wi128_0, (1,3) w/ wi128_1
        {
            float2 t = cmul(wi128_0, v[2]);
            float2 a = v[0];
            v[0] = cadd(a, t); v[2] = csub(a, t);
            t = cmul(wi128_1, v[3]);
            a = v[1];
            v[1] = cadd(a, t); v[3] = csub(a, t);
        }

#pragma unroll
        for (int j = 0; j < 4; ++j) {
            acc += __builtin_amdgcn_sqrtf(v[j].x * v[j].x + v[j].y * v[j].y);
        }
    }

#pragma unroll
    for (int off = 32; off > 0; off >>= 1) acc += __shfl_xor(acc, off, 64);

    if (lane == 0) {
        const float focused = acc * (1.0f / (256.0f * 256.0f * 3.0f));
        out[task] = (focused > 0.3f) ? focused : 0.0f;
    }
}

extern "C" void kernel_launch(void* const* d_in, const int* in_sizes, int n_in,
                              void* d_out, int out_size, void* d_ws, size_t ws_size,
                              hipStream_t stream) {
    (void)in_sizes; (void)n_in; (void)out_size; (void)ws_size;
    const float* stim = (const float*)d_in[0];   // (32, 32768)
    const float* Hr   = (const float*)d_in[1];   // (512, 256, 3)
    const float* Hi   = (const float*)d_in[2];   // (512, 256, 3)
    float* out = (float*)d_out;                  // (32, 512)

    float2* y  = (float2*)d_ws;                                                     // 8 MB
    float2* Ht = (float2*)((char*)d_ws + (size_t)32 * 128 * 256 * sizeof(float2));  // 3 MB

    k_prep<<<1024 + 1536, 256, 0, stream>>>(stim, y, Hr, Hi, Ht);
    k_fft_cols<<<32 * 8, 256, 0, stream>>>(y);
    k_recon<<<16384 / 4, 256, 0, stream>>>(y, Ht, out);
}

// Round 7
// 45.644 us; speedup vs baseline: 2.2367x; 1.1874x over previous
//
#include <hip/hip_runtime.h>
#include <math.h>

// Problem: stimulus (32, 128*256) f32; H_real/H_imag (512, 256, 3) f32; out (32, 512) f32.
//   qf = fft2(q) over (128, 256)  [separable]
//   per (b,m): r = m%128; acc = sum_w sum_d |ifft256(qf[b,r,:] * H[m,:,w])|
//   out = acc/(256*256*3), thresholded at 0.3   (unit-modulus ref_beams vanish under |.|)
//
// Forward k-axis FFT is DIF (natural in -> bitrev out); recon inverse is DIT (bitrev in
// -> natural out); pointwise multiply lives in bitrev space (H pre-permuted once).
// 256-pt FFTs are register-resident; cross-lane exchange plan (per float2):
//   h=1,2   : DPP quad_perm (VALU, ~2cyc)          [0xB1 = xor1, 0x4E = xor2]
//   h=4,8   : __shfl_xor (LDS pipe; known-good)
//   h=16,32 : v_permlane16/32_swap_b32 (VALU, gfx950) -> uniform butterfly v' = a + S*b
// The 3 wavelength iFFTs in k_recon are interleaved (12 independent chains) to hide
// shuffle latency. All loops fully unrolled -> static register indexing.

#define TWO_PI 6.28318530717958647692f
#define PI_F   3.14159265358979323846f

#if __has_builtin(__builtin_amdgcn_permlane16_swap)
#define USE_PL16 1
#else
#define USE_PL16 0
#endif
#if __has_builtin(__builtin_amdgcn_permlane32_swap)
#define USE_PL32 1
#else
#define USE_PL32 0
#endif

typedef unsigned int uint2v __attribute__((ext_vector_type(2)));

__device__ inline float2 cmul(float2 a, float2 b) {
    return make_float2(a.x * b.x - a.y * b.y, a.x * b.y + a.y * b.x);
}
__device__ inline float2 cadd(float2 a, float2 b) { return make_float2(a.x + b.x, a.y + b.y); }
__device__ inline float2 csub(float2 a, float2 b) { return make_float2(a.x - b.x, a.y - b.y); }

// v' = A*v + B*o (complex, 8 fma-class ops)
__device__ inline float2 ab2(float2 A, float2 v, float2 B, float2 o) {
    return make_float2(A.x * v.x - A.y * v.y + B.x * o.x - B.y * o.y,
                       A.x * v.y + A.y * v.x + B.x * o.y + B.y * o.x);
}
// a + S*b (complex, 4 fma)
__device__ inline float2 cfma2(float2 S, float2 b, float2 a) {
    return make_float2(fmaf(S.x, b.x, fmaf(-S.y, b.y, a.x)),
                       fmaf(S.x, b.y, fmaf( S.y, b.x, a.y)));
}
__device__ inline float2 shfl_xor_c(float2 v, int mask) {
    return make_float2(__shfl_xor(v.x, mask, 64), __shfl_xor(v.y, mask, 64));
}

#define DPP_XOR1 0xB1  // quad_perm [1,0,3,2]
#define DPP_XOR2 0x4E  // quad_perm [2,3,0,1]
template <int CTRL>
__device__ inline float2 dpp_quad(float2 v) {
    return make_float2(
        __int_as_float(__builtin_amdgcn_update_dpp(__float_as_int(v.x), __float_as_int(v.x),
                                                   CTRL, 0xF, 0xF, false)),
        __int_as_float(__builtin_amdgcn_update_dpp(__float_as_int(v.y), __float_as_int(v.y),
                                                   CTRL, 0xF, 0xF, false)));
}

#if USE_PL16
// a = (lane&16)? partner : self ; b = (lane&16)? self : partner
__device__ inline void swap16c(float2 v, float2& a, float2& b) {
    uint2v rx = __builtin_amdgcn_permlane16_swap(__float_as_uint(v.x), __float_as_uint(v.x), false, false);
    uint2v ry = __builtin_amdgcn_permlane16_swap(__float_as_uint(v.y), __float_as_uint(v.y), false, false);
    a = make_float2(__uint_as_float(rx[0]), __uint_as_float(ry[0]));
    b = make_float2(__uint_as_float(rx[1]), __uint_as_float(ry[1]));
}
#endif
#if USE_PL32
__device__ inline void swap32c(float2 v, float2& a, float2& b) {
    uint2v rx = __builtin_amdgcn_permlane32_swap(__float_as_uint(v.x), __float_as_uint(v.x), false, false);
    uint2v ry = __builtin_amdgcn_permlane32_swap(__float_as_uint(v.y), __float_as_uint(v.y), false, false);
    a = make_float2(__uint_as_float(rx[0]), __uint_as_float(ry[0]));
    b = make_float2(__uint_as_float(rx[1]), __uint_as_float(ry[1]));
}
#endif

// ---------------- Pass 1 (fused): row FFTs + H transpose/bitrev ------------------
// blocks [0,1024): 256-pt forward DIF FFT per row (4096 rows, 1 wave each).
// blocks [1024,2560): Ht[m][w][p] = (Hr+i*Hi)[m][brev8(p)][w].
__global__ __launch_bounds__(256) void k_prep(const float* __restrict__ x,
                                              float2* __restrict__ y,
                                              const float* __restrict__ Hr,
                                              const float* __restrict__ Hi,
                                              float2* __restrict__ Ht) {
    if (blockIdx.x >= 1024) {
        const int idx = (blockIdx.x - 1024) * 256 + threadIdx.x;  // < 512*768
        const int m = idx / 768;
        const int rem = idx - m * 768;
        const int w = rem >> 8;
        const int p = rem & 255;
        const int k = __brev((unsigned)p) >> 24;
        const int src = (m * 256 + k) * 3 + w;
        Ht[idx] = make_float2(Hr[src], Hi[src]);
        return;
    }

    const int lane = threadIdx.x & 63;
    const int wid  = blockIdx.x * 4 + (threadIdx.x >> 6);   // row id 0..4095
    const float fl = (float)lane;
    float sn, cs;

    // in-register stage twiddles (forward, sign -)
    __sincosf(-TWO_PI * fl * (1.0f / 256.0f), &sn, &cs);
    const float2 w128_0 = make_float2(cs, sn);
    const float2 w128_1 = make_float2(w128_0.y, -w128_0.x);
    __sincosf(-TWO_PI * fl * (1.0f / 128.0f), &sn, &cs);
    const float2 w64f = make_float2(cs, sn);

    // cross-lane constants; W_h = exp(-i pi (lane&(h-1))/h), up = lane&h
    float2 W;
    __sincosf(-PI_F * (float)(lane & 31) * (1.0f / 32.0f), &sn, &cs);
    W = make_float2(cs, sn);
#if USE_PL32
    const float2 P32 = (lane & 32) ? W : make_float2(1.0f, 0.0f);
    const float2 Q32 = (lane & 32) ? make_float2(-W.x, -W.y) : make_float2(1.0f, 0.0f);
#else
    const float2 A32f = (lane & 32) ? make_float2(-W.x, -W.y) : make_float2(1.0f, 0.0f);
    const float2 B32f = (lane & 32) ? W : make_float2(1.0f, 0.0f);
#endif
    __sincosf(-PI_F * (float)(lane & 15) * (1.0f / 16.0f), &sn, &cs);
    W = make_float2(cs, sn);
#if USE_PL16
    const float2 P16 = (lane & 16) ? W : make_float2(1.0f, 0.0f);
    const float2 Q16 = (lane & 16) ? make_float2(-W.x, -W.y) : make_float2(1.0f, 0.0f);
#else
    const float2 A16f = (lane & 16) ? make_float2(-W.x, -W.y) : make_float2(1.0f, 0.0f);
    const float2 B16f = (lane & 16) ? W : make_float2(1.0f, 0.0f);
#endif
    __sincosf(-PI_F * (float)(lane & 7) * 0.125f, &sn, &cs);
    W = make_float2(cs, sn);
    const float2 A8f = (lane & 8) ? make_float2(-W.x, -W.y) : make_float2(1.0f, 0.0f);
    const float2 B8f = (lane & 8) ? W : make_float2(1.0f, 0.0f);
    __sincosf(-PI_F * (float)(lane & 3) * 0.25f, &sn, &cs);
    W = make_float2(cs, sn);
    const float2 A4f = (lane & 4) ? make_float2(-W.x, -W.y) : make_float2(1.0f, 0.0f);
    const float2 B4f = (lane & 4) ? W : make_float2(1.0f, 0.0f);
    __sincosf(-PI_F * (float)(lane & 1) * 0.5f, &sn, &cs);
    W = make_float2(cs, sn);
    const float2 A2f = (lane & 2) ? make_float2(-W.x, -W.y) : make_float2(1.0f, 0.0f);
    const float2 B2f = (lane & 2) ? W : make_float2(1.0f, 0.0f);
    const float sgn1 = (lane & 1) ? -1.0f : 1.0f;

    const float* xr = x + (size_t)wid * 256;
    float2 v[4];
    v[0] = make_float2(xr[lane],       0.0f);
    v[1] = make_float2(xr[64 + lane],  0.0f);
    v[2] = make_float2(xr[128 + lane], 0.0f);
    v[3] = make_float2(xr[192 + lane], 0.0f);

    // DIF h=128: (v0,v2),(v1,v3)
    { float2 a = v[0], b = v[2]; v[0] = cadd(a, b); v[2] = cmul(csub(a, b), w128_0); }
    { float2 a = v[1], b = v[3]; v[1] = cadd(a, b); v[3] = cmul(csub(a, b), w128_1); }
    // DIF h=64: (v0,v1),(v2,v3)
    { float2 a = v[0], b = v[1]; v[0] = cadd(a, b); v[1] = cmul(csub(a, b), w64f); }
    { float2 a = v[2], b = v[3]; v[2] = cadd(a, b); v[3] = cmul(csub(a, b), w64f); }

    // h=32
#pragma unroll
    for (int j = 0; j < 4; ++j) {
#if USE_PL32
        float2 a, bb; swap32c(v[j], a, bb);
        v[j] = ab2(P32, a, Q32, bb);
#else
        const float2 o = shfl_xor_c(v[j], 32);
        v[j] = ab2(A32f, v[j], B32f, o);
#endif
    }
    // h=16
#pragma unroll
    for (int j = 0; j < 4; ++j) {
#if USE_PL16
        float2 a, bb; swap16c(v[j], a, bb);
        v[j] = ab2(P16, a, Q16, bb);
#else
        const float2 o = shfl_xor_c(v[j], 16);
        v[j] = ab2(A16f, v[j], B16f, o);
#endif
    }
    // h=8, h=4 (shfl)
#pragma unroll
    for (int j = 0; j < 4; ++j) {
        const float2 o = shfl_xor_c(v[j], 8);
        v[j] = ab2(A8f, v[j], B8f, o);
    }
#pragma unroll
    for (int j = 0; j < 4; ++j) {
        const float2 o = shfl_xor_c(v[j], 4);
        v[j] = ab2(A4f, v[j], B4f, o);
    }
    // h=2 (DPP)
#pragma unroll
    for (int j = 0; j < 4; ++j) {
        const float2 o = dpp_quad<DPP_XOR2>(v[j]);
        v[j] = ab2(A2f, v[j], B2f, o);
    }
    // h=1 (DPP, W==1): down v+o, up o-v
#pragma unroll
    for (int j = 0; j < 4; ++j) {
        const float2 o = dpp_quad<DPP_XOR1>(v[j]);
        v[j] = make_float2(fmaf(sgn1, v[j].x, o.x), fmaf(sgn1, v[j].y, o.y));
    }

    float2* yr = y + (size_t)wid * 256;
#pragma unroll
    for (int j = 0; j < 4; ++j) yr[j * 64 + lane] = v[j];
}

// ---------------- Pass 2: 128-pt forward DIT FFT along r, in place (LDS) ---------
// grid = B * 16 tiles (16 k-slots each) = 512 blocks, 256 threads.
__global__ __launch_bounds__(256) void k_fft_cols(float2* __restrict__ y) {
    __shared__ float2 sm[128][17];
    __shared__ float2 tw[64];
    const int tid = threadIdx.x;

    if (tid < 64) {
        float sn, cs;
        __sincosf(-TWO_PI * (float)tid * (1.0f / 128.0f), &sn, &cs);
        tw[tid] = make_float2(cs, sn);
    }

    const int b  = blockIdx.x >> 4;
    const int d0 = (blockIdx.x & 15) << 4;
    const int c  = tid & 15;
    const int r0 = tid >> 4;  // 0..15
    const size_t base = ((size_t)b * 128) * 256 + (size_t)d0 + (size_t)c;

#pragma unroll
    for (int r = r0; r < 128; r += 16) {
        sm[__brev((unsigned)r) >> 25][c] = y[base + (size_t)r * 256];
    }
    __syncthreads();

#pragma unroll
    for (int st = 0; st < 7; ++st) {
        const int half = 1 << st;
#pragma unroll
        for (int k = 0; k < 4; ++k) {  // 64 butterflies x 16 cols / 256 threads
            const int idx = tid + (k << 8);
            const int cc  = idx & 15;
            const int j   = idx >> 4;  // 0..63
            const int pos = j & (half - 1);
            const int i0  = (j << 1) - pos;
            const int i1  = i0 + half;
            const float2 w  = tw[pos << (6 - st)];
            const float2 a  = sm[i0][cc];
            const float2 bv = cmul(sm[i1][cc], w);
            sm[i0][cc] = cadd(a, bv);
            sm[i1][cc] = csub(a, bv);
        }
        __syncthreads();
    }

#pragma unroll
    for (int r = r0; r < 128; r += 16) {
        y[base + (size_t)r * 256] = sm[r][c];
    }
}

// ---------------- Pass 3: per (b,m): 3x inverse 256-pt DIT FFT, interleaved ------
__global__ __launch_bounds__(256) void k_recon(const float2* __restrict__ qf,
                                               const float2* __restrict__ Ht,
                                               float* __restrict__ out) {
    const int lane = threadIdx.x & 63;
    const int task = blockIdx.x * 4 + (threadIdx.x >> 6);  // b*512 + m
    const int b = task >> 9;
    const int m = task & 511;
    const int r = m & 127;
    const float fl = (float)lane;
    float sn, cs;

    // DIT stage constants (inverse, sign +): W_h = exp(+i pi (lane&(h-1))/h)
    const float sgn1 = (lane & 1) ? -1.0f : 1.0f;
    float2 W;
    __sincosf(PI_F * (float)(lane & 1) * 0.5f, &sn, &cs);
    W = make_float2(cs, sn);
    const float2 A2 = (lane & 2) ? make_float2(-W.x, -W.y) : make_float2(1.0f, 0.0f);
    const float2 B2 = (lane & 2) ? make_float2(1.0f, 0.0f) : W;
    __sincosf(PI_F * (float)(lane & 3) * 0.25f, &sn, &cs);
    W = make_float2(cs, sn);
    const float2 A4 = (lane & 4) ? make_float2(-W.x, -W.y) : make_float2(1.0f, 0.0f);
    const float2 B4 = (lane & 4) ? make_float2(1.0f, 0.0f) : W;
    __sincosf(PI_F * (float)(lane & 7) * 0.125f, &sn, &cs);
    W = make_float2(cs, sn);
    const float2 A8 = (lane & 8) ? make_float2(-W.x, -W.y) : make_float2(1.0f, 0.0f);
    const float2 B8 = (lane & 8) ? make_float2(1.0f, 0.0f) : W;
    __sincosf(PI_F * (float)(lane & 15) * (1.0f / 16.0f), &sn, &cs);
    W = make_float2(cs, sn);
#if USE_PL16
    const float2 S16 = (lane & 16) ? make_float2(-W.x, -W.y) : W;
#else
    const float2 A16 = (lane & 16) ? make_float2(-W.x, -W.y) : make_float2(1.0f, 0.0f);
    const float2 B16 = (lane & 16) ? make_float2(1.0f, 0.0f) : W;
#endif
    __sincosf(PI_F * (float)(lane & 31) * (1.0f / 32.0f), &sn, &cs);
    W = make_float2(cs, sn);
#if USE_PL32
    const float2 S32 = (lane & 32) ? make_float2(-W.x, -W.y) : W;
#else
    const float2 A32 = (lane & 32) ? make_float2(-W.x, -W.y) : make_float2(1.0f, 0.0f);
    const float2 B32 = (lane & 32) ? make_float2(1.0f, 0.0f) : W;
#endif
    __sincosf(TWO_PI * fl * (1.0f / 128.0f), &sn, &cs);
    const float2 w64 = make_float2(cs, sn);
    __sincosf(TWO_PI * fl * (1.0f / 256.0f), &sn, &cs);
    const float2 wi0 = make_float2(cs, sn);
    const float2 wi1 = make_float2(-wi0.y, wi0.x);

    const float2* q = qf + ((size_t)(b * 128 + r)) * 256;
    float2 qv[4];
#pragma unroll
    for (int j = 0; j < 4; ++j) qv[j] = q[j * 64 + lane];

    const float2* hp = Ht + (size_t)m * 768;
    float2 v[3][4];
#pragma unroll
    for (int w = 0; w < 3; ++w)
#pragma unroll
        for (int j = 0; j < 4; ++j)
            v[w][j] = cmul(qv[j], hp[w * 256 + j * 64 + lane]);

    // h=1 (DPP, W==1): down v+o, up o-v
#pragma unroll
    for (int w = 0; w < 3; ++w)
#pragma unroll
        for (int j = 0; j < 4; ++j) {
            const float2 o = dpp_quad<DPP_XOR1>(v[w][j]);
            v[w][j] = make_float2(fmaf(sgn1, v[w][j].x, o.x), fmaf(sgn1, v[w][j].y, o.y));
        }
    // h=2 (DPP)
#pragma unroll
    for (int w = 0; w < 3; ++w)
#pragma unroll
        for (int j = 0; j < 4; ++j) {
            const float2 o = dpp_quad<DPP_XOR2>(v[w][j]);
            v[w][j] = ab2(A2, v[w][j], B2, o);
        }
    // h=4 (shfl)
#pragma unroll
    for (int w = 0; w < 3; ++w)
#pragma unroll
        for (int j = 0; j < 4; ++j) {
            const float2 o = shfl_xor_c(v[w][j], 4);
            v[w][j] = ab2(A4, v[w][j], B4, o);
        }
    // h=8 (shfl)
#pragma unroll
    for (int w = 0; w < 3; ++w)
#pragma unroll
        for (int j = 0; j < 4; ++j) {
            const float2 o = shfl_xor_c(v[w][j], 8);
            v[w][j] = ab2(A8, v[w][j], B8, o);
        }
    // h=16 (permlane16_swap): v' = a + S16*b
#pragma unroll
    for (int w = 0; w < 3; ++w)
#pragma unroll
        for (int j = 0; j < 4; ++j) {
#if USE_PL16
            float2 a, bb; swap16c(v[w][j], a, bb);
            v[w][j] = cfma2(S16, bb, a);
#else
            const float2 o = shfl_xor_c(v[w][j], 16);
            v[w][j] = ab2(A16, v[w][j], B16, o);
#endif
        }
    // h=32 (permlane32_swap): v' = a + S32*b
#pragma unroll
    for (int w = 0; w < 3; ++w)
#pragma unroll
        for (int j = 0; j < 4; ++j) {
#if USE_PL32
            float2 a, bb; swap32c(v[w][j], a, bb);
            v[w][j] = cfma2(S32, bb, a);
#else
            const float2 o = shfl_xor_c(v[w][j], 32);
            v[w][j] = ab2(A32, v[w][j], B32, o);
#endif
        }
    // in-register h=64, h=128
#pragma unroll
    for (int w = 0; w < 3; ++w) {
        float2 t = cmul(w64, v[w][1]);
        float2 a = v[w][0];
        v[w][0] = cadd(a, t); v[w][1] = csub(a, t);
        t = cmul(w64, v[w][3]);
        a = v[w][2];
        v[w][2] = cadd(a, t); v[w][3] = csub(a, t);
        t = cmul(wi0, v[w][2]);
        a = v[w][0];
        v[w][0] = cadd(a, t); v[w][2] = csub(a, t);
        t = cmul(wi1, v[w][3]);
        a = v[w][1];
        v[w][1] = cadd(a, t); v[w][3] = csub(a, t);
    }

    float acc = 0.0f;
#pragma unroll
    for (int w = 0; w < 3; ++w)
#pragma unroll
        for (int j = 0; j < 4; ++j)
            acc += __builtin_amdgcn_sqrtf(v[w][j].x * v[w][j].x + v[w][j].y * v[w][j].y);

#pragma unroll
    for (int off = 32; off > 0; off >>= 1) acc += __shfl_xor(acc, off, 64);

    if (lane == 0) {
        const float focused = acc * (1.0f / (256.0f * 256.0f * 3.0f));
        out[task] = (focused > 0.3f) ? focused : 0.0f;
    }
}

extern "C" void kernel_launch(void* const* d_in, const int* in_sizes, int n_in,
                              void* d_out, int out_size, void* d_ws, size_t ws_size,
                              hipStream_t stream) {
    (void)in_sizes; (void)n_in; (void)out_size; (void)ws_size;
    const float* stim = (const float*)d_in[0];   // (32, 32768)
    const float* Hr   = (const float*)d_in[1];   // (512, 256, 3)
    const float* Hi   = (const float*)d_in[2];   // (512, 256, 3)
    float* out = (float*)d_out;                  // (32, 512)

    float2* y  = (float2*)d_ws;                                                     // 8 MB
    float2* Ht = (float2*)((char*)d_ws + (size_t)32 * 128 * 256 * sizeof(float2));  // 3 MB

    k_prep<<<1024 + 1536, 256, 0, stream>>>(stim, y, Hr, Hi, Ht);
    k_fft_cols<<<32 * 16, 256, 0, stream>>>(y);
    k_recon<<<16384 / 4, 256, 0, stream>>>(y, Ht, out);
}